// Round 8
// baseline (270.657 us; speedup 1.0000x reference)
//
#include <hip/hip_runtime.h>

typedef unsigned short u16;
typedef __attribute__((ext_vector_type(8))) short bf16x8;
typedef __attribute__((ext_vector_type(8))) unsigned short u16x8;
typedef __attribute__((ext_vector_type(4))) float f32x4;

#define AS1 __attribute__((address_space(1)))
#define AS3 __attribute__((address_space(3)))
#define SBAR __builtin_amdgcn_sched_barrier(0)
#define LG0  asm volatile("s_waitcnt lgkmcnt(0)" ::: "memory")

static __device__ __forceinline__ u16 f2bf(float f) {
  unsigned u = __float_as_uint(f);
  u += 0x7FFFu + ((u >> 16) & 1u);   // RNE
  return (u16)(u >> 16);
}
static __device__ __forceinline__ float bf2f(u16 h) {
  return __uint_as_float(((unsigned)h) << 16);
}

// ---------- fp32 -> bf16 converts ----------
__global__ __launch_bounds__(256) void conv_big(const float* __restrict__ e,
                                                const float* __restrict__ res,
                                                u16* __restrict__ eb, u16* __restrict__ rb) {
  int i = blockIdx.x * 256 + threadIdx.x;
  const float* in = blockIdx.z ? res : e;
  u16* out = blockIdx.z ? rb : eb;
  const float4* p = (const float4*)in + (size_t)i * 2;
  float4 a = p[0], b = p[1];
  u16x8 r;
  r[0] = f2bf(a.x); r[1] = f2bf(a.y); r[2] = f2bf(a.z); r[3] = f2bf(a.w);
  r[4] = f2bf(b.x); r[5] = f2bf(b.y); r[6] = f2bf(b.z); r[7] = f2bf(b.w);
  ((u16x8*)out)[i] = r;
}
__global__ __launch_bounds__(256) void conv_w(const float* __restrict__ w0,
                                              const float* __restrict__ w1,
                                              const float* __restrict__ w2,
                                              u16* __restrict__ o0, u16* __restrict__ o1,
                                              u16* __restrict__ o2) {
  int i = blockIdx.x * 256 + threadIdx.x;
  const float* in = blockIdx.z == 0 ? w0 : (blockIdx.z == 1 ? w1 : w2);
  u16* out = blockIdx.z == 0 ? o0 : (blockIdx.z == 1 ? o1 : o2);
  const float4* p = (const float4*)in + (size_t)i * 2;
  float4 a = p[0], b = p[1];
  u16x8 r;
  r[0] = f2bf(a.x); r[1] = f2bf(a.y); r[2] = f2bf(a.z); r[3] = f2bf(a.w);
  r[4] = f2bf(b.x); r[5] = f2bf(b.y); r[6] = f2bf(b.z); r[7] = f2bf(b.w);
  ((u16x8*)out)[i] = r;
}

// ---------- row-sum of K (bf16, 1024 cols) -> fp32 ----------
__global__ __launch_bounds__(256) void ksum_kernel(const u16* __restrict__ K,
                                                   float* __restrict__ out) {
  int row = blockIdx.x * 4 + (threadIdx.x >> 6);
  int lane = threadIdx.x & 63;
  const u16x8* p = (const u16x8*)(K + (size_t)row * 1024);
  float s = 0.f;
#pragma unroll
  for (int it = 0; it < 2; ++it) {
    u16x8 v = p[lane + it * 64];
#pragma unroll
    for (int j = 0; j < 8; ++j) s += bf2f(v[j]);
  }
#pragma unroll
  for (int off = 32; off >= 1; off >>= 1) s += __shfl_down(s, off);
  if (lane == 0) out[row] = s;
}

enum { M_BIASN = 0, M_BIASM = 1, M_SCORES = 2, M_OUT = 3 };

// =============== 256x256 bf16 8-phase ring engine (T2+T3+T4+T5) ===============
// C = A(MxK) * B(NxK)^T. 8 waves (2M x 4N, wave tile 128x64). LDS = 9-slot
// ring of 16KB units (144KB); tile t = units {A-lo,A-hi,B-lo,B-hi} at slots
// (4t+j) mod 9. Prefetch lookahead 5 units (2+2 issued in phases 0-1); ONE
// counted s_waitcnt vmcnt(2) per K-tile (tile-t units landed, deeper units
// stay in flight across barriers). Stage-issue strictly after the phase
// barrier => slot overwrite is ordered after all prior reads (race-free).
#define MM16(mb, af_, bf_)                                                      \
  { _Pragma("unroll") for (int m_ = 0; m_ < 4; ++m_)                            \
      _Pragma("unroll") for (int n_ = 0; n_ < 4; ++n_)                          \
        acc[(mb) + m_][n_] = __builtin_amdgcn_mfma_f32_16x16x32_bf16(           \
            af_[m_], bf_[n_], acc[(mb) + m_][n_], 0, 0, 0); }

#define ISSUE(ui_, slot_)                                                       \
  {                                                                             \
    const int p_ = (ui_) & 3;                                                   \
    const u16* src_ = (p_ < 2) ? A : B;                                         \
    const int ld_ = (p_ < 2) ? lda : ldb;                                       \
    const int r0_ = ((p_ < 2) ? m0 : n0) + (p_ & 1) * 128;                      \
    const int k0_ = ((ui_) >> 2) * 64;                                          \
    char* dst_ = smem + (slot_) * 16384;                                        \
    _Pragma("unroll") for (int h_ = 0; h_ < 2; ++h_) {                          \
      const char* g_ = (const char*)(src_ + (size_t)(r0_ + h_ * 64 + strow) * ld_ + k0_) + gcol; \
      __builtin_amdgcn_global_load_lds((const AS1 void*)g_,                     \
          (AS3 void*)(dst_ + h_ * 8192 + sdst), 16, 0, 0);                      \
    }                                                                           \
  }

template <int MODE>
static __device__ __forceinline__ void engine256(
    const u16* __restrict__ A, int lda, const u16* __restrict__ B, int ldb,
    char* smem, int m0, int n0, int nk, void* __restrict__ Cbase, int ldc,
    const float* __restrict__ bias) {
  const int tid = threadIdx.x;
  const int lane = tid & 63;
  const int wid = tid >> 6;
  const int wm = wid >> 2, wn = wid & 3;   // 2 x 4 wave grid

  // staging geometry (512 thr x 16B = 8KB = 64 rows per issue; source col
  // carries the inverse XOR swizzle, LDS dest linear)
  const int strow = tid >> 3;                          // 0..63
  const int gcol = ((tid & 7) << 4) ^ ((strow & 7) << 4);
  const int sdst = tid << 4;

  // ds_read constants (row r has r&7 == lane&7)
  const int roff = (lane & 15) * 128;
  const int c0 = ((0 + (lane >> 4)) ^ (lane & 7)) << 4;
  const int c1 = ((4 + (lane >> 4)) ^ (lane & 7)) << 4;

  f32x4 acc[8][4];
#pragma unroll
  for (int m = 0; m < 8; ++m)
#pragma unroll
    for (int n = 0; n < 4; ++n) acc[m][n] = (f32x4){0.f, 0.f, 0.f, 0.f};

  // prologue: units 0..4 (tile0 complete + tile1 A-lo)
#pragma unroll
  for (int u = 0; u < 5; ++u) ISSUE(u, u);
  int ui = 5, si = 5;
  int sbase = 0;
  const int lim = 4 * nk;

  for (int t = 0; t < nk; ++t) {
    int sA = sbase + wm; if (sA >= 9) sA -= 9;
    int sB = sbase + 2 + (wn >> 1); if (sB >= 9) sB -= 9;
    const char* Au = smem + sA * 16384;
    const char* Bu = smem + sB * 16384 + (wn & 1) * 8192;
    bf16x8 afa[4], afb[4], bfa[4], bfb[4];

    // ---- phase 0: counted wait (tile-t units landed; deeper stay in flight)
    if (t + 1 == nk) { asm volatile("s_waitcnt vmcnt(0)" ::: "memory"); }
    else             { asm volatile("s_waitcnt vmcnt(2)" ::: "memory"); }
    __builtin_amdgcn_s_barrier();
    if (ui < lim) { ISSUE(ui, si); ++ui; if (++si == 9) si = 0; }
    if (ui < lim) { ISSUE(ui, si); ++ui; if (++si == 9) si = 0; }
#pragma unroll
    for (int f = 0; f < 4; ++f) afa[f] = *(const bf16x8*)(Au + f * 2048 + roff + c0);
#pragma unroll
    for (int f = 0; f < 4; ++f) bfa[f] = *(const bf16x8*)(Bu + f * 2048 + roff + c0);
    LG0; SBAR;
    __builtin_amdgcn_s_setprio(1);
    MM16(0, afa, bfa);
    __builtin_amdgcn_s_setprio(0);

    // ---- phase 1
    __builtin_amdgcn_s_barrier();
    if (ui < lim) { ISSUE(ui, si); ++ui; if (++si == 9) si = 0; }
    if (ui < lim) { ISSUE(ui, si); ++ui; if (++si == 9) si = 0; }
#pragma unroll
    for (int f = 0; f < 4; ++f) afb[f] = *(const bf16x8*)(Au + 8192 + f * 2048 + roff + c0);
    LG0; SBAR;
    __builtin_amdgcn_s_setprio(1);
    MM16(4, afb, bfa);
    __builtin_amdgcn_s_setprio(0);

    // ---- phase 2
    __builtin_amdgcn_s_barrier();
#pragma unroll
    for (int f = 0; f < 4; ++f) afa[f] = *(const bf16x8*)(Au + f * 2048 + roff + c1);
#pragma unroll
    for (int f = 0; f < 4; ++f) bfb[f] = *(const bf16x8*)(Bu + f * 2048 + roff + c1);
    LG0; SBAR;
    __builtin_amdgcn_s_setprio(1);
    MM16(0, afa, bfb);
    __builtin_amdgcn_s_setprio(0);

    // ---- phase 3
    __builtin_amdgcn_s_barrier();
#pragma unroll
    for (int f = 0; f < 4; ++f) afb[f] = *(const bf16x8*)(Au + 8192 + f * 2048 + roff + c1);
    LG0; SBAR;
    __builtin_amdgcn_s_setprio(1);
    MM16(4, afb, bfb);
    __builtin_amdgcn_s_setprio(0);

    sbase += 4; if (sbase >= 9) sbase -= 9;
  }

  // epilogue — C/D layout: col = lane&15, row = (lane>>4)*4 + reg  [m89]
  u16* C16 = (u16*)Cbase;
#pragma unroll
  for (int m = 0; m < 8; ++m) {
#pragma unroll
    for (int n = 0; n < 4; ++n) {
      const int rb = m0 + wm * 128 + m * 16 + ((lane >> 4) << 2);
      const int c = n0 + wn * 64 + n * 16 + (lane & 15);
#pragma unroll
      for (int j = 0; j < 4; ++j) {
        const int r = rb + j;
        float v = acc[m][n][j];
        v += (MODE == M_BIASN) ? bias[c] : bias[r];
        C16[(size_t)r * ldc + c] = f2bf(v);
      }
    }
  }
}

// ---- Q+K projections on the 8-phase engine: flat 512 blocks, per-XCD strips
__global__ __launch_bounds__(512, 2) void k_qk_proj(
    const u16* eb, const u16* rb, const u16* Wq, const u16* Wk,
    const float* bq, const float* bk, u16* Q, u16* K) {
  const int l = blockIdx.x;
  const int xcd = l & 7;
  const int idx = l >> 3;            // 0..63
  const bool isK = idx >= 32;
  const int j = idx & 31;
  const int gy = xcd * 8 + (j >> 2);  // M-tile (256) in [0,64)
  const int gx = j & 3;               // N-tile (256) in [0,4)
  const u16* A = isK ? rb : eb;
  const u16* B = isK ? Wk : Wq;
  const float* bias = isK ? bk : bq;
  u16* C = isK ? K : Q;
  __shared__ char smem[147456];
  engine256<M_BIASN>(A, 1024, B, 1024, smem, gy * 256, gx * 256, 16, C, 1024, bias);
}
// ---- V^T = Wv @ e^T + bv on the 8-phase engine: 256 blocks = 1/CU
__global__ __launch_bounds__(512, 2) void k_v_proj(
    const u16* Wv, const u16* eb, u16* VT, const float* bv) {
  const int l = blockIdx.x;
  const int xcd = l & 7;
  const int idx = l >> 3;              // 0..31
  const int gxt = xcd * 8 + (idx >> 2);  // t-tile (256) in [0,64)
  const int gyd = idx & 3;               // d-tile (256) in [0,4)
  __shared__ char smem[147456];
  engine256<M_BIASM>(Wv, 1024, eb, 1024, smem, gyd * 256, gxt * 256, 16,
                     VT, 16384, bv);
}

// =============== 128x128 bf16 GEMM core (m97 + T2 swizzle) — scores/out ======
template <int MODE>
static __device__ __forceinline__ void core128(
    const u16* __restrict__ Ab, int lda, const u16* __restrict__ Bb, int ldb,
    char* smem, int m0, int n0, int nk, void* __restrict__ Cbase, int ldc,
    const float* __restrict__ bias, const float* __restrict__ ksb,
    const float* __restrict__ vtab) {
  const int tid = threadIdx.x;
  const int lane = tid & 63;
  const int wid = tid >> 6;
  const int wm = wid >> 1, wn = wid & 1;

  char* As = smem;           // 128 rows x 128B = 16KB
  char* Bs = smem + 16384;   // 16KB

  const int rbase_st = tid >> 3;                 // 0..31
  const int gcol = ((tid & 7) << 4) ^ ((rbase_st & 7) << 4);

  const int aoff = (wm * 64 + (lane & 15)) * 128;
  const int boff = (wn * 64 + (lane & 15)) * 128;
  const int c0 = ((0 * 4 + (lane >> 4)) ^ (lane & 7)) << 4;
  const int c1 = ((1 * 4 + (lane >> 4)) ^ (lane & 7)) << 4;

  f32x4 acc[4][4];
#pragma unroll
  for (int m = 0; m < 4; ++m)
#pragma unroll
    for (int n = 0; n < 4; ++n) acc[m][n] = (f32x4){0.f, 0.f, 0.f, 0.f};

  for (int kt = 0; kt < nk; ++kt) {
    const int k0 = kt * 64;
#pragma unroll
    for (int i = 0; i < 4; ++i) {
      const char* ga = (const char*)(Ab + (size_t)(m0 + i * 32 + rbase_st) * lda + k0) + gcol;
      __builtin_amdgcn_global_load_lds(
          (const AS1 void*)ga, (AS3 void*)(As + i * 4096 + wid * 1024), 16, 0, 0);
    }
#pragma unroll
    for (int i = 0; i < 4; ++i) {
      const char* gb = (const char*)(Bb + (size_t)(n0 + i * 32 + rbase_st) * ldb + k0) + gcol;
      __builtin_amdgcn_global_load_lds(
          (const AS1 void*)gb, (AS3 void*)(Bs + i * 4096 + wid * 1024), 16, 0, 0);
    }
    __syncthreads();
#pragma unroll
    for (int ks = 0; ks < 2; ++ks) {
      const int cks = ks ? c1 : c0;
      bf16x8 af[4], bfv[4];
#pragma unroll
      for (int m = 0; m < 4; ++m) af[m] = *(const bf16x8*)(As + aoff + m * 2048 + cks);
#pragma unroll
      for (int n = 0; n < 4; ++n) bfv[n] = *(const bf16x8*)(Bs + boff + n * 2048 + cks);
#pragma unroll
      for (int m = 0; m < 4; ++m)
#pragma unroll
        for (int n = 0; n < 4; ++n)
          acc[m][n] = __builtin_amdgcn_mfma_f32_16x16x32_bf16(af[m], bfv[n], acc[m][n], 0, 0, 0);
    }
    __syncthreads();
  }

  u16* C16 = (u16*)Cbase;
  float* Cf = (float*)Cbase;
#pragma unroll
  for (int m = 0; m < 4; ++m) {
#pragma unroll
    for (int n = 0; n < 4; ++n) {
      const int rb = m0 + wm * 64 + m * 16 + ((lane >> 4) << 2);
      const int c = n0 + wn * 64 + n * 16 + (lane & 15);
#pragma unroll
      for (int j = 0; j < 4; ++j) {
        const int r = rb + j;
        float v = acc[m][n][j];
        if (MODE == M_SCORES) {
          if (c <= r) v += ksb[r] * vtab[r - c];  // rel = t-s >= 0
          else v = 0.f;                           // causal mask
          C16[(size_t)r * ldc + c] = f2bf(v);
        } else {  // M_OUT
          Cf[(size_t)r * ldc + c] = v;
        }
      }
    }
  }
}

// ---- scores: flat 1088 blocks; xcd = l&7 = z (batch pinned to XCD)
__global__ __launch_bounds__(256, 4) void k_scores(
    const u16* Q, const u16* K, u16* S, const float* ksum, const float* vtab) {
  const int l = blockIdx.x;
  const int z = l & 7;
  const int h = l >> 3;
  int gy = 0;
#pragma unroll
  for (int q = 1; q < 16; ++q) if (q * (q + 1) / 2 <= h) gy = q;
  const int gx = h - gy * (gy + 1) / 2;  // gx <= gy
  __shared__ char smem[32768];
  core128<M_SCORES>(Q + (size_t)z * 2048 * 1024, 1024,
                    K + (size_t)z * 2048 * 1024, 1024, smem,
                    gy * 128, gx * 128, 16,
                    S + (size_t)z * 2048 * 2048, 2048,
                    nullptr, ksum + (size_t)z * 2048, vtab);
}
// ---- out: flat 1024 blocks; xcd = z; gy descending (longest-first)
__global__ __launch_bounds__(256, 4) void k_out(
    const u16* S, const u16* VT, float* O) {
  const int l = blockIdx.x;
  const int z = l & 7;
  const int idx = l >> 3;              // 0..127
  const int gy = 15 - (idx >> 3);      // q-tile, 15..0
  const int gx = idx & 7;              // d-tile
  const int nk = (gy + 1) * 2;         // causal extent (gy+1)*128 score-cols
  __shared__ char smem[32768];
  core128<M_OUT>(S + (size_t)z * 2048 * 2048, 2048,
                 VT + (size_t)z * 2048, 16384, smem,
                 gy * 128, gx * 128, nk,
                 O + (size_t)z * 2048 * 1024, 1024,
                 nullptr, nullptr, nullptr);
}

extern "C" void kernel_launch(void* const* d_in, const int* in_sizes, int n_in,
                              void* d_out, int out_size, void* d_ws, size_t ws_size,
                              hipStream_t stream) {
  (void)in_sizes; (void)n_in; (void)out_size; (void)ws_size;
  const float* e    = (const float*)d_in[0];
  const float* res  = (const float*)d_in[1];
  const float* Wq_w = (const float*)d_in[2];
  const float* Wq_b = (const float*)d_in[3];
  const float* Wk_w = (const float*)d_in[4];
  const float* Wk_b = (const float*)d_in[5];
  const float* Wv_w = (const float*)d_in[6];
  const float* Wv_b = (const float*)d_in[7];
  const float* vtab = (const float*)d_in[8];

  char* ws = (char*)d_ws;
  const size_t SZ = 33554432;  // 32 MiB = one bf16 (16384x1024) buffer
  u16* ebf = (u16*)(ws);
  u16* rbf = (u16*)(ws + SZ);
  u16* Qb  = (u16*)(ws + 2 * SZ);
  u16* Kb  = (u16*)(ws + 3 * SZ);
  u16* VT  = (u16*)(ws + 4 * SZ);
  u16* Wqb = (u16*)(ws + 5 * SZ);
  u16* Wkb = (u16*)(ws + 5 * SZ + 2097152);
  u16* Wvb = (u16*)(ws + 5 * SZ + 2 * 2097152);
  float* ksum = (float*)(ws + 5 * SZ + 3 * 2097152);
  u16* scores = (u16*)(ws);  // reuse ebf+rbf (64 MB); written after last read of ebf

  conv_big<<<dim3(8192, 1, 2), 256, 0, stream>>>(e, res, ebf, rbf);
  conv_w<<<dim3(512, 1, 3), 256, 0, stream>>>(Wq_w, Wk_w, Wv_w, Wqb, Wkb, Wvb);

  // Q/K projections: 512 flat blocks, 8-phase 256^2 engine
  k_qk_proj<<<dim3(512, 1, 1), 512, 0, stream>>>(ebf, rbf, Wqb, Wkb, Wq_b, Wk_b, Qb, Kb);
  // V^T: 256 flat blocks (1/CU), 8-phase 256^2 engine
  k_v_proj<<<dim3(256, 1, 1), 512, 0, stream>>>(Wvb, ebf, VT, Wv_b);

  ksum_kernel<<<4096, 256, 0, stream>>>(Kb, ksum);

  // scores: 1088 flat blocks, batch z pinned to XCD z
  k_scores<<<dim3(1088, 1, 1), 256, 0, stream>>>(Qb, Kb, scores, ksum, vtab);

  // out: 1024 flat blocks, batch z pinned to XCD z, longest tiles first
  k_out<<<dim3(1024, 1, 1), 256, 0, stream>>>(scores, VT, (float*)d_out);
}